// Round 4
// baseline (180.331 us; speedup 1.0000x reference)
//
#include <hip/hip_runtime.h>
#include <math.h>

#define BB   256
#define SS   512
#define VV   150
#define INW  512
#define NPOS (BB * SS)      // 131072
#define GRID_A 2048         // 64 positions per block
#define GRID_B 2048
#define EPSF 1e-8f

// ws layout:
// [0,32768)         float4 pA[2048]   {gathered_sum, mask_cnt, eos_logp_sum, eos_cnt}
// [32768,40960)     float  pB[2048]   attention partials
// [40960,44032)     int    pC[768]    rep counts per (row,n)
// [44032,45056)     int    hasx[256]  (has_t && !has_p) per row
// [45056,176128)    uchar  toks[131072] argmax tokens
//
// INSTRUMENTATION ROUND: kern_a and kern_b are each launched TWICE
// (identical, deterministic). dur_us - 108.2 ≈ T_a + T_b gives direct
// attribution of stream time vs fixed overhead.

// ---- predictions: 64 rows staged in LDS, 4 segment-threads per row ----
__global__ __launch_bounds__(256) void kern_a(
    const float* __restrict__ pred, const int* __restrict__ tgt,
    float4* __restrict__ pA, unsigned char* __restrict__ toks)
{
    __shared__ __align__(16) float slab[64 * VV + 2];
    __shared__ float shp[16];
    const int tid  = threadIdx.x;
    const int lane = tid & 63;
    const int wid  = tid >> 6;
    const int base = blockIdx.x * 64;

    // stage 64 rows = 2400 float4, perfectly coalesced
    const float4* g4 = (const float4*)(pred + (size_t)base * VV);
    float4* l4 = (float4*)slab;
    #pragma unroll
    for (int k = 0; k < 10; ++k) {
        const int i = tid + k * 256;
        if (i < 2400) l4[i] = g4[i];
    }
    __syncthreads();

    const int p  = tid >> 2;          // row within block (0..63)
    const int s  = tid & 3;           // segment (cols s*38 .. min(s*38+37,149))
    const int c0 = s * 38;
    const float* row = slab + p * VV;
    const float2* row2 = (const float2*)(row + c0);
    const int t = tgt[base + p];      // quad-uniform

    // pass 1: per-segment max + first-index argmax
    float m = -INFINITY; int mi = 200;
    #pragma unroll
    for (int j = 0; j < 19; ++j) {
        const float2 v = row2[j];
        const int c = c0 + 2 * j;
        if (c     < VV && v.x > m) { m = v.x; mi = c; }
        if (c + 1 < VV && v.y > m) { m = v.y; mi = c + 1; }
    }
    // combine 4 segments within the quad (lanes p*4+s)
    {
        float om = __shfl_xor(m, 1); int oi = __shfl_xor(mi, 1);
        if (om > m || (om == m && oi < mi)) { m = om; mi = oi; }
        om = __shfl_xor(m, 2); oi = __shfl_xor(mi, 2);
        if (om > m || (om == m && oi < mi)) { m = om; mi = oi; }
    }

    float acc_g = 0.f, acc_mc = 0.f, acc_el = 0.f, acc_ec = 0.f;
    if (t != 0) {
        if (s == t / 38) acc_g = row[t];
        if (s == 0)      acc_mc = 1.f;
    }
    if (t == 2) {                     // quad-uniform branch; shuffles stay in-quad
        float sx = 0.f;
        #pragma unroll
        for (int j = 0; j < 19; ++j) {
            const float2 v = row2[j];
            const int c = c0 + 2 * j;
            if (c     < VV) sx += __expf(v.x - m);
            if (c + 1 < VV) sx += __expf(v.y - m);
        }
        sx += __shfl_xor(sx, 1);
        sx += __shfl_xor(sx, 2);
        if (s == 0) {
            acc_el = __logf(__expf(row[2] - m) / sx + EPSF);
            acc_ec = 1.f;
        }
    }
    if (s == 0) toks[base + p] = (unsigned char)mi;

    // block reduction of 4 accumulators
    #pragma unroll
    for (int off = 32; off > 0; off >>= 1) {
        acc_g  += __shfl_xor(acc_g,  off);
        acc_mc += __shfl_xor(acc_mc, off);
        acc_el += __shfl_xor(acc_el, off);
        acc_ec += __shfl_xor(acc_ec, off);
    }
    if (lane == 0) {
        shp[wid * 4 + 0] = acc_g;  shp[wid * 4 + 1] = acc_mc;
        shp[wid * 4 + 2] = acc_el; shp[wid * 4 + 3] = acc_ec;
    }
    __syncthreads();
    if (tid == 0) {
        float4 r;
        r.x = shp[0] + shp[4] + shp[8]  + shp[12];
        r.y = shp[1] + shp[5] + shp[9]  + shp[13];
        r.z = shp[2] + shp[6] + shp[10] + shp[14];
        r.w = shp[3] + shp[7] + shp[11] + shp[15];
        pA[blockIdx.x] = r;
    }
}

// ---- attention entropy: pure float4 streaming ----
__global__ __launch_bounds__(256) void kern_b(
    const float* __restrict__ attw, float* __restrict__ pB)
{
    __shared__ float shp[4];
    const int tid  = threadIdx.x;
    const int lane = tid & 63;
    const int wid  = tid >> 6;
    const float4* a4 = (const float4*)attw;
    const size_t stride = (size_t)GRID_B * 256;
    const size_t i0 = (size_t)blockIdx.x * 256 + tid;
    float s = 0.f;
    #pragma unroll 8
    for (int it = 0; it < 32; ++it) {               // 32*stride == 16,777,216
        const float4 v = a4[i0 + (size_t)it * stride];
        s += v.x * __logf(v.x + EPSF) + v.y * __logf(v.y + EPSF)
           + v.z * __logf(v.z + EPSF) + v.w * __logf(v.w + EPSF);
    }
    #pragma unroll
    for (int off = 32; off > 0; off >>= 1) s += __shfl_xor(s, off);
    if (lane == 0) shp[wid] = s;
    __syncthreads();
    if (tid == 0) pB[blockIdx.x] = shp[0] + shp[1] + shp[2] + shp[3];
}

// one block per (row, n): blocks 0..255 -> n=2, 256..511 -> n=3, 512..767 -> n=4
// n=2 blocks additionally compute hasx[b] = has_eos(targets) && !has_eos(pred)
__global__ __launch_bounds__(256) void kern_c(
    const unsigned char* __restrict__ toks, const int* __restrict__ tgt,
    int* __restrict__ pC, int* __restrict__ hasx)
{
    const int blk = blockIdx.x;
    const int b = blk & 255;
    const int n = 2 + (blk >> 8);
    const int L = SS - n + 1;

    __shared__ int tok[SS];
    __shared__ __align__(16) int h[SS];
    __shared__ int sflags;

    if (threadIdx.x == 0) sflags = 0;
    const unsigned char* rt = toks + b * SS;
    tok[threadIdx.x]       = rt[threadIdx.x];
    tok[threadIdx.x + 256] = rt[threadIdx.x + 256];
    __syncthreads();

    if (blk < 256) {
        const int* trow = tgt + b * SS;
        int f = 0;
        if (trow[threadIdx.x] == 2 || trow[threadIdx.x + 256] == 2) f |= 1;
        if (tok[threadIdx.x] == 2 || tok[threadIdx.x + 256] == 2)   f |= 2;
        if (f) atomicOr(&sflags, f);
    }

    #pragma unroll
    for (int q = 0; q < 2; ++q) {
        const int i = threadIdx.x + q * 256;
        int hv;
        if (i < L) {
            hv = tok[i];
            int mul = VV;
            for (int j = 1; j < n; ++j) { hv += tok[i + j] * mul; mul *= VV; }
        } else {
            hv = 0x7F000000 + i;   // unique sentinel, > any real hash (~5.06e8)
        }
        h[i] = hv;
    }
    __syncthreads();

    const int i1 = threadIdx.x, i2 = threadIdx.x + 256;
    const int h1 = h[i1], h2 = h[i2];
    int c1 = 0, c2 = 0;
    #pragma unroll 4
    for (int j = 0; j < SS; j += 4) {
        const int4 hv = *(const int4*)&h[j];
        c1 += (hv.x == h1 && j     < i1) + (hv.y == h1 && j + 1 < i1)
            + (hv.z == h1 && j + 2 < i1) + (hv.w == h1 && j + 3 < i1);
        c2 += (hv.x == h2 && j     < i2) + (hv.y == h2 && j + 1 < i2)
            + (hv.z == h2 && j + 2 < i2) + (hv.w == h2 && j + 3 < i2);
    }
    int rep = (c1 >= 2) + (c2 >= 2);
    #pragma unroll
    for (int off = 32; off > 0; off >>= 1) rep += __shfl_xor(rep, off);
    __shared__ int w4[4];
    if ((threadIdx.x & 63) == 0) w4[threadIdx.x >> 6] = rep;
    __syncthreads();
    if (threadIdx.x == 0) {
        pC[blk] = w4[0] + w4[1] + w4[2] + w4[3];
        if (blk < 256) hasx[b] = ((sflags & 1) && !(sflags & 2)) ? 1 : 0;
    }
}

__global__ __launch_bounds__(256) void kern_f(
    const int* __restrict__ hasx, const float4* __restrict__ pA,
    const float* __restrict__ pB, const int* __restrict__ pC,
    float* __restrict__ out)
{
    const int tid  = threadIdx.x;
    const int lane = tid & 63;
    const int wid  = tid >> 6;
    double v[9];
    #pragma unroll
    for (int k = 0; k < 9; ++k) v[k] = 0.0;

    for (int i = tid; i < GRID_A; i += 256) {
        const float4 p = pA[i];
        v[0] += p.x; v[1] += p.y; v[2] += p.z; v[3] += p.w;
    }
    for (int i = tid; i < GRID_B; i += 256) v[4] += pB[i];
    v[5] = pC[tid]; v[6] = pC[tid + 256]; v[7] = pC[tid + 512];
    v[8] = (double)hasx[tid];

    #pragma unroll
    for (int off = 32; off > 0; off >>= 1)
        #pragma unroll
        for (int k = 0; k < 9; ++k) v[k] += __shfl_xor(v[k], off);

    __shared__ double sd[4][9];
    if (lane == 0)
        for (int k = 0; k < 9; ++k) sd[wid][k] = v[k];
    __syncthreads();

    if (tid == 0) {
        double r[9];
        for (int k = 0; k < 9; ++k) r[k] = sd[0][k] + sd[1][k] + sd[2][k] + sd[3][k];
        const double mainv    = -r[0] / fmax(r[1], 1.0);
        const double eos_loss = (r[3] > 0.0) ? (-r[2] / (double)NPOS) : 0.0;
        const double no_eos   = r[8] / (double)BB;
        const double eos_tot  = eos_loss + 0.5 * no_eos;
        const double att      = 0.1 * r[4] / (double)NPOS;  // = -mean(ent)*0.1
        const double pattern  = (0.2 * r[5] + 0.3 * r[6] + 0.4 * r[7]) / (double)BB;
        const double total    = mainv + 0.1 * pattern + 0.2 * eos_tot + 0.05 * att;
        out[0] = (float)total;   out[1] = (float)mainv; out[2] = (float)pattern;
        out[3] = (float)eos_tot; out[4] = (float)att;
    }
}

extern "C" void kernel_launch(void* const* d_in, const int* in_sizes, int n_in,
                              void* d_out, int out_size, void* d_ws, size_t ws_size,
                              hipStream_t stream)
{
    const float* pred = (const float*)d_in[0];
    const int*   tgt  = (const int*)d_in[1];
    const float* attw = (const float*)d_in[2];
    float* out = (float*)d_out;
    char*  ws  = (char*)d_ws;

    float4* pA   = (float4*)ws;
    float*  pB   = (float*)(ws + 32768);
    int*    pC   = (int*)(ws + 40960);
    int*    hasx = (int*)(ws + 44032);
    unsigned char* toks = (unsigned char*)(ws + 45056);

    // Instrumentation: a,b duplicated (interleaved so dups stay L3-cold).
    // dur_us - 108.2 ≈ T_a + T_b.
    kern_a<<<GRID_A, 256, 0, stream>>>(pred, tgt, pA, toks);
    kern_b<<<GRID_B, 256, 0, stream>>>(attw, pB);
    kern_a<<<GRID_A, 256, 0, stream>>>(pred, tgt, pA, toks);
    kern_b<<<GRID_B, 256, 0, stream>>>(attw, pB);
    kern_c<<<768, 256, 0, stream>>>(toks, tgt, pC, hasx);
    kern_f<<<1, 256, 0, stream>>>(hasx, pA, pB, pC, out);
}

// Round 5
// 100.609 us; speedup vs baseline: 1.7924x; 1.7924x over previous
//
#include <hip/hip_runtime.h>
#include <math.h>

#define BB   256
#define SS   512
#define VV   150
#define INW  512
#define NPOS (BB * SS)      // 131072
#define GRID 2048
#define EPSF 1e-8f

typedef float vf4 __attribute__((ext_vector_type(4)));

// ws layout:
// [0,32768)         float4 pA[2048]   {gathered_sum, mask_cnt, eos_logp_sum, eos_cnt}
// [32768,40960)     float  pB[2048]   attention partials
// [40960,44032)     int    pC[768]    rep counts per (row,n)
// [44032,45056)     int    hasx[256]  (has_t && !has_p) per row
// [45056,45060)     int    counter    (ticket for last-block reduce)
// [45312,176384)    uchar  toks[131072] argmax tokens

// ---- fused: phase A = predictions (wave per position), phase B = attw chunk ----
__global__ __launch_bounds__(256) void kern_ab(
    const float* __restrict__ pred, const int* __restrict__ tgt,
    const float* __restrict__ attw, float4* __restrict__ pA,
    float* __restrict__ pB, unsigned char* __restrict__ toks,
    int* __restrict__ counter)
{
    __shared__ float shp[16];
    __shared__ float shb[4];
    const int tid  = threadIdx.x;
    const int lane = tid & 63;
    const int wid  = tid >> 6;

    if (blockIdx.x == 0 && tid == 0) *counter = 0;   // re-arm ticket each call

    // ================= phase A: predictions =================
    const int gw = blockIdx.x * 4 + wid;             // 0..8191
    float s_g = 0.f, s_mc = 0.f, s_el = 0.f, s_ec = 0.f;
    for (int it = 0; it < 16; ++it) {
        const int pos = gw + it * 8192;
        const float* row = pred + (size_t)pos * VV;
        const float v0 = row[lane];
        const float v1 = row[lane + 64];
        const bool  l3 = lane < (VV - 128);          // 22 lanes
        const float v2 = l3 ? row[lane + 128] : -INFINITY;

        float m = fmaxf(fmaxf(v0, v1), v2);
        #pragma unroll
        for (int off = 32; off > 0; off >>= 1)
            m = fmaxf(m, __shfl_xor(m, off));
        int li = (v0 == m) ? lane : (v1 == m) ? lane + 64
                 : (l3 && v2 == m) ? lane + 128 : (1 << 20);
        #pragma unroll
        for (int off = 32; off > 0; off >>= 1)
            li = min(li, __shfl_xor(li, off));

        const int t = tgt[pos];                      // wave-uniform
        const float src = (t < 64) ? v0 : (t < 128) ? v1 : v2;
        const float g = __shfl(src, t & 63);

        if (t == 2) {                                // rare, wave-uniform
            float ex = __expf(v0 - m) + __expf(v1 - m)
                     + (l3 ? __expf(v2 - m) : 0.f);
            #pragma unroll
            for (int off = 32; off > 0; off >>= 1)
                ex += __shfl_xor(ex, off);
            const float p2 = __shfl(v0, 2);
            if (lane == 0) {
                s_el += __logf(__expf(p2 - m) / ex + EPSF);
                s_ec += 1.f;
            }
        }
        if (lane == 0) {
            toks[pos] = (unsigned char)li;
            if (t != 0) { s_g += g; s_mc += 1.f; }
        }
    }
    if (lane == 0) {
        shp[wid * 4 + 0] = s_g;  shp[wid * 4 + 1] = s_mc;
        shp[wid * 4 + 2] = s_el; shp[wid * 4 + 3] = s_ec;
    }

    // ================= phase B: attention entropy, contiguous chunk =========
    const vf4* a4 = (const vf4*)attw;
    const size_t base = (size_t)blockIdx.x * 8192;   // 8192 float4 = 131 KB/block
    float s = 0.f;
    #pragma unroll 8
    for (int it = 0; it < 32; ++it) {
        const vf4 v = __builtin_nontemporal_load(a4 + base + it * 256 + tid);
        s += v.x * __logf(v.x + EPSF) + v.y * __logf(v.y + EPSF)
           + v.z * __logf(v.z + EPSF) + v.w * __logf(v.w + EPSF);
    }
    #pragma unroll
    for (int off = 32; off > 0; off >>= 1) s += __shfl_xor(s, off);
    if (lane == 0) shb[wid] = s;

    __syncthreads();
    if (tid == 0) {
        float4 r;
        r.x = shp[0] + shp[4] + shp[8]  + shp[12];
        r.y = shp[1] + shp[5] + shp[9]  + shp[13];
        r.z = shp[2] + shp[6] + shp[10] + shp[14];
        r.w = shp[3] + shp[7] + shp[11] + shp[15];
        pA[blockIdx.x] = r;
        pB[blockIdx.x] = shb[0] + shb[1] + shb[2] + shb[3];
    }
}

// ---- n-gram penalty (768 blocks) + last-block final reduce ----
__global__ __launch_bounds__(256) void kern_cf(
    const unsigned char* __restrict__ toks, const int* __restrict__ tgt,
    int* __restrict__ pC, int* __restrict__ hasx, int* __restrict__ counter,
    const float4* __restrict__ pA, const float* __restrict__ pB,
    float* __restrict__ out)
{
    const int blk = blockIdx.x;
    const int b = blk & 255;
    const int n = 2 + (blk >> 8);
    const int L = SS - n + 1;
    const int tid = threadIdx.x;

    __shared__ int tok[SS];
    __shared__ __align__(16) int h[SS];
    __shared__ int sflags;
    __shared__ int sticket;

    if (tid == 0) sflags = 0;
    const unsigned char* rt = toks + b * SS;
    tok[tid]       = rt[tid];
    tok[tid + 256] = rt[tid + 256];
    __syncthreads();

    if (blk < 256) {
        const int* trow = tgt + b * SS;
        int f = 0;
        if (trow[tid] == 2 || trow[tid + 256] == 2) f |= 1;
        if (tok[tid] == 2 || tok[tid + 256] == 2)   f |= 2;
        if (f) atomicOr(&sflags, f);
    }

    #pragma unroll
    for (int q = 0; q < 2; ++q) {
        const int i = tid + q * 256;
        int hv;
        if (i < L) {
            hv = tok[i];
            int mul = VV;
            for (int j = 1; j < n; ++j) { hv += tok[i + j] * mul; mul *= VV; }
        } else {
            hv = 0x7F000000 + i;   // unique sentinel, > any real hash (~5.06e8)
        }
        h[i] = hv;
    }
    __syncthreads();

    const int i1 = tid, i2 = tid + 256;
    const int h1 = h[i1], h2 = h[i2];
    int c1 = 0, c2 = 0;
    #pragma unroll 4
    for (int j = 0; j < SS; j += 4) {
        const int4 hv = *(const int4*)&h[j];
        c1 += (hv.x == h1 && j     < i1) + (hv.y == h1 && j + 1 < i1)
            + (hv.z == h1 && j + 2 < i1) + (hv.w == h1 && j + 3 < i1);
        c2 += (hv.x == h2 && j     < i2) + (hv.y == h2 && j + 1 < i2)
            + (hv.z == h2 && j + 2 < i2) + (hv.w == h2 && j + 3 < i2);
    }
    int rep = (c1 >= 2) + (c2 >= 2);
    #pragma unroll
    for (int off = 32; off > 0; off >>= 1) rep += __shfl_xor(rep, off);
    __shared__ int w4[4];
    if ((tid & 63) == 0) w4[tid >> 6] = rep;
    __syncthreads();
    if (tid == 0) {
        pC[blk] = w4[0] + w4[1] + w4[2] + w4[3];
        if (blk < 256) hasx[b] = ((sflags & 1) && !(sflags & 2)) ? 1 : 0;
        __threadfence();                      // publish before ticket
        sticket = atomicAdd(counter, 1);
    }
    __syncthreads();
    if (sticket != 768 - 1) return;

    // ---- last block: final reduce (deterministic: fixed-order sums) ----
    __threadfence();                          // acquire others' pC/hasx
    const int lane = tid & 63;
    const int wid  = tid >> 6;
    double v[9];
    #pragma unroll
    for (int k = 0; k < 9; ++k) v[k] = 0.0;
    for (int i = tid; i < GRID; i += 256) {
        const float4 p = pA[i];
        v[0] += p.x; v[1] += p.y; v[2] += p.z; v[3] += p.w;
    }
    for (int i = tid; i < GRID; i += 256) v[4] += pB[i];
    v[5] = pC[tid]; v[6] = pC[tid + 256]; v[7] = pC[tid + 512];
    v[8] = (double)hasx[tid];

    #pragma unroll
    for (int off = 32; off > 0; off >>= 1)
        #pragma unroll
        for (int k = 0; k < 9; ++k) v[k] += __shfl_xor(v[k], off);

    __shared__ double sd[4][9];
    if (lane == 0)
        for (int k = 0; k < 9; ++k) sd[wid][k] = v[k];
    __syncthreads();

    if (tid == 0) {
        double r[9];
        for (int k = 0; k < 9; ++k) r[k] = sd[0][k] + sd[1][k] + sd[2][k] + sd[3][k];
        const double mainv    = -r[0] / fmax(r[1], 1.0);
        const double eos_loss = (r[3] > 0.0) ? (-r[2] / (double)NPOS) : 0.0;
        const double no_eos   = r[8] / (double)BB;
        const double eos_tot  = eos_loss + 0.5 * no_eos;
        const double att      = 0.1 * r[4] / (double)NPOS;  // = -mean(ent)*0.1
        const double pattern  = (0.2 * r[5] + 0.3 * r[6] + 0.4 * r[7]) / (double)BB;
        const double total    = mainv + 0.1 * pattern + 0.2 * eos_tot + 0.05 * att;
        out[0] = (float)total;   out[1] = (float)mainv; out[2] = (float)pattern;
        out[3] = (float)eos_tot; out[4] = (float)att;
    }
}

extern "C" void kernel_launch(void* const* d_in, const int* in_sizes, int n_in,
                              void* d_out, int out_size, void* d_ws, size_t ws_size,
                              hipStream_t stream)
{
    const float* pred = (const float*)d_in[0];
    const int*   tgt  = (const int*)d_in[1];
    const float* attw = (const float*)d_in[2];
    float* out = (float*)d_out;
    char*  ws  = (char*)d_ws;

    float4* pA   = (float4*)ws;
    float*  pB   = (float*)(ws + 32768);
    int*    pC   = (int*)(ws + 40960);
    int*    hasx = (int*)(ws + 44032);
    int*    cnt  = (int*)(ws + 45056);
    unsigned char* toks = (unsigned char*)(ws + 45312);

    kern_ab<<<GRID, 256, 0, stream>>>(pred, tgt, attw, pA, pB, toks, cnt);
    kern_cf<<<768, 256, 0, stream>>>(toks, tgt, pC, hasx, cnt, pA, pB, out);
}